// Round 2
// baseline (386.507 us; speedup 1.0000x reference)
//
#include <hip/hip_runtime.h>
#include <stdint.h>

typedef __attribute__((ext_vector_type(8))) short short8;
typedef __attribute__((ext_vector_type(4))) float floatx4;
typedef unsigned short ushort_t;

#define E_TOTAL 640000
#define N_NODES 20000
#define M_BLK   128
#define XS_LD   264   // 256 + 8 fp16 pad -> row stride 528B
#define HS_LD   136   // 128 + 8 fp16 pad -> row stride 272B

__device__ __forceinline__ unsigned short f2h(float f){
    _Float16 h = (_Float16)f;                  // v_cvt_f16_f32, RNE
    union { _Float16 h; unsigned short u; } v; v.h = h; return v.u;
}
__device__ __forceinline__ unsigned pk2h(float a, float b){
    return (unsigned)f2h(a) | ((unsigned)f2h(b) << 16);
}

// Repack W1[256,128] and W2[128,64] (row-major fp32) into fp16 MFMA
// B-fragment order: lane's 8 B-elements contiguous (one 16B load).
//   W1p[((kt*8+nt)*64 + lane)*8 + j] = fp16(W1[kt*32 + (lane>>4)*8 + j][nt*16 + (lane&15)])
__global__ void repack_w(const float* __restrict__ W1,
                         const float* __restrict__ W2,
                         ushort_t* __restrict__ W1p,
                         ushort_t* __restrict__ W2p){
    int tid = blockIdx.x * 256 + threadIdx.x;
    if (tid < 8*8*64){
        int kt = tid >> 9, nt = (tid >> 6) & 7, l = tid & 63;
        int q = l >> 4, c = l & 15;
        ushort_t tmp[8];
        #pragma unroll
        for (int j = 0; j < 8; j++)
            tmp[j] = f2h(W1[(kt*32 + q*8 + j)*128 + nt*16 + c]);
        #pragma unroll
        for (int j = 0; j < 8; j++) W1p[tid*8 + j] = tmp[j];
    } else if (tid < 8*8*64 + 4*4*64){
        int t = tid - 8*8*64;
        int kt = t >> 8, nt = (t >> 6) & 3, l = t & 63;
        int q = l >> 4, c = l & 15;
        ushort_t tmp[8];
        #pragma unroll
        for (int j = 0; j < 8; j++)
            tmp[j] = f2h(W2[(kt*32 + q*8 + j)*64 + nt*16 + c]);
        #pragma unroll
        for (int j = 0; j < 8; j++) W2p[t*8 + j] = tmp[j];
    }
}

__global__ __launch_bounds__(256, 2)
void edge_mlp(const float* __restrict__ node_attr,
              const float* __restrict__ edge_attr,
              const float* __restrict__ global_attr,
              const float* __restrict__ node_mask,
              const float* __restrict__ edge_mask,
              const int*   __restrict__ edge_index,
              const int*   __restrict__ eg_index,
              const float* __restrict__ b1,
              const float* __restrict__ b2,
              const ushort_t* __restrict__ W1p,
              const ushort_t* __restrict__ W2p,
              float*       __restrict__ out){
    __shared__ ushort_t Xs[M_BLK * XS_LD];   // 67584 B; re-used as Hs after barrier
    __shared__ int sidx[M_BLK], ridx[M_BLK], gidx[M_BLK];
    __shared__ float ems[M_BLK];
    ushort_t* Hs = Xs;                        // [M_BLK][HS_LD] overlay

    const int tid = threadIdx.x;
    const int e0  = blockIdx.x * M_BLK;

    // ---- stage indices + edge mask tile ----
    if (tid < M_BLK){
        sidx[tid] = edge_index[e0 + tid];
        ridx[tid] = edge_index[E_TOTAL + e0 + tid];
        gidx[tid] = eg_index[e0 + tid];
        ems[tid]  = edge_mask[e0 + tid];
    }
    // ---- seg0: edge_attr rows (fp32), coalesced float4, cvt->fp16 ----
    {
        const float4* src = (const float4*)(edge_attr + (size_t)e0 * 64);
        #pragma unroll
        for (int k = 0; k < 8; k++){
            int idx = tid + k*256;            // 0..2047 ; 16 float4 per row
            int r = idx >> 4, c = idx & 15;
            float4 v = src[idx];
            uint2 o; o.x = pk2h(v.x, v.y); o.y = pk2h(v.z, v.w);
            *(uint2*)&Xs[r*XS_LD + c*4] = o;
        }
    }
    __syncthreads();   // idx arrays visible
    // ---- seg3: global gather (16 distinct rows, L2-hot) ----
    {
        #pragma unroll
        for (int k = 0; k < 8; k++){
            int idx = tid + k*256; int r = idx >> 4, c = idx & 15;
            const float4* src = (const float4*)(global_attr + (size_t)gidx[r] * 64);
            float4 v = src[c];
            uint2 o; o.x = pk2h(v.x, v.y); o.y = pk2h(v.z, v.w);
            *(uint2*)&Xs[r*XS_LD + 192 + c*4] = o;
        }
    }
    // ---- seg1/seg2: node gathers with node_mask scaling ----
    {
        int r = tid >> 1, s = tid & 1;
        int idx = s ? ridx[r] : sidx[r];
        float m = node_mask[idx];
        const float4* src = (const float4*)(node_attr + (size_t)idx * 64);
        ushort_t* dst = &Xs[r*XS_LD + 64 + s*64];
        #pragma unroll
        for (int c2 = 0; c2 < 8; c2++){
            float4 a = src[2*c2], b = src[2*c2+1];
            uint4 o;
            o.x = pk2h(a.x*m, a.y*m); o.y = pk2h(a.z*m, a.w*m);
            o.z = pk2h(b.x*m, b.y*m); o.w = pk2h(b.z*m, b.w*m);
            *(uint4*)(dst + c2*8) = o;
        }
    }
    __syncthreads();

    // ---- GEMM1: H[128,128] = X[128,256] @ W1 ; wave owns 4x4 MFMA tiles ----
    const int w  = tid >> 6, lane = tid & 63;
    const int q  = lane >> 4, cc = lane & 15;
    const int mt0 = (w >> 1) * 4;   // 0 or 4
    const int nt0 = (w & 1) * 4;    // 0 or 4

    floatx4 acc[4][4];
    #pragma unroll
    for (int i = 0; i < 4; i++)
        #pragma unroll
        for (int j = 0; j < 4; j++) acc[i][j] = (floatx4){0.f,0.f,0.f,0.f};

    const short8* W1v = (const short8*)W1p;
    #pragma unroll
    for (int kt = 0; kt < 8; kt++){
        short8 b[4];
        #pragma unroll
        for (int j = 0; j < 4; j++) b[j] = W1v[(kt*8 + nt0 + j)*64 + lane];
        #pragma unroll
        for (int i = 0; i < 4; i++){
            const short8 a = *(const short8*)&Xs[((mt0 + i)*16 + cc)*XS_LD + kt*32 + q*8];
            #pragma unroll
            for (int j = 0; j < 4; j++)
                acc[i][j] = __builtin_amdgcn_mfma_f32_16x16x32_f16(a, b[j], acc[i][j], 0, 0, 0);
        }
    }
    __syncthreads();   // everyone done reading Xs before Hs overlay

    // ---- epilogue 1: +b1, relu, fp16 -> Hs (MFMA-A layout = row-major) ----
    #pragma unroll
    for (int j = 0; j < 4; j++){
        int col = (nt0 + j)*16 + cc;
        float bb = b1[col];
        #pragma unroll
        for (int i = 0; i < 4; i++){
            int rowb = (mt0 + i)*16 + q*4;
            #pragma unroll
            for (int r = 0; r < 4; r++){
                float v = acc[i][j][r] + bb;
                v = v > 0.f ? v : 0.f;
                Hs[(rowb + r)*HS_LD + col] = f2h(v);
            }
        }
    }
    __syncthreads();

    // ---- GEMM2: OUT[128,64] = H[128,128] @ W2 ; wave owns 2 M-tiles x 4 N-tiles ----
    floatx4 acc2[2][4];
    #pragma unroll
    for (int i = 0; i < 2; i++)
        #pragma unroll
        for (int j = 0; j < 4; j++) acc2[i][j] = (floatx4){0.f,0.f,0.f,0.f};

    const short8* W2v = (const short8*)W2p;
    #pragma unroll
    for (int kt = 0; kt < 4; kt++){
        short8 b[4];
        #pragma unroll
        for (int j = 0; j < 4; j++) b[j] = W2v[(kt*4 + j)*64 + lane];
        #pragma unroll
        for (int i = 0; i < 2; i++){
            const short8 a = *(const short8*)&Hs[((2*w + i)*16 + cc)*HS_LD + kt*32 + q*8];
            #pragma unroll
            for (int j = 0; j < 4; j++)
                acc2[i][j] = __builtin_amdgcn_mfma_f32_16x16x32_f16(a, b[j], acc2[i][j], 0, 0, 0);
        }
    }

    // ---- epilogue 2: +b2, *edge_mask, store fp32 ----
    float bb2[4];
    #pragma unroll
    for (int j = 0; j < 4; j++) bb2[j] = b2[j*16 + cc];
    #pragma unroll
    for (int i = 0; i < 2; i++){
        #pragma unroll
        for (int r = 0; r < 4; r++){
            int row = (2*w + i)*16 + q*4 + r;
            float em = ems[row];
            size_t base = (size_t)(e0 + row) * 64;
            #pragma unroll
            for (int j = 0; j < 4; j++){
                float v = (acc2[i][j][r] + bb2[j]) * em;
                out[base + j*16 + cc] = v;
            }
        }
    }
}

extern "C" void kernel_launch(void* const* d_in, const int* in_sizes, int n_in,
                              void* d_out, int out_size, void* d_ws, size_t ws_size,
                              hipStream_t stream){
    const float* node_attr   = (const float*)d_in[0];
    const float* edge_attr   = (const float*)d_in[1];
    const float* global_attr = (const float*)d_in[2];
    const float* node_mask   = (const float*)d_in[3];
    const float* edge_mask   = (const float*)d_in[4];
    const int*   edge_index  = (const int*)d_in[5];
    const int*   eg_index    = (const int*)d_in[6];
    const float* W1          = (const float*)d_in[7];
    const float* b1          = (const float*)d_in[8];
    const float* W2          = (const float*)d_in[9];
    const float* b2          = (const float*)d_in[10];

    ushort_t* W1p = (ushort_t*)d_ws;            // 8*8*64*8 = 32768 elems (64 KB)
    ushort_t* W2p = W1p + 8*8*64*8;             // 4*4*64*8 =  8192 elems (16 KB)

    repack_w<<<20, 256, 0, stream>>>(W1, W2, W1p, W2p);
    edge_mlp<<<E_TOTAL / M_BLK, 256, 0, stream>>>(
        node_attr, edge_attr, global_attr, node_mask, edge_mask,
        edge_index, eg_index, b1, b2, W1p, W2p, (float*)d_out);
}

// Round 3
// 380.680 us; speedup vs baseline: 1.0153x; 1.0153x over previous
//
#include <hip/hip_runtime.h>
#include <stdint.h>

typedef __attribute__((ext_vector_type(8))) short short8;
typedef __attribute__((ext_vector_type(4))) float floatx4;
typedef unsigned short ushort_t;

#define E_TOTAL 640000
#define M_BLK   128
#define XS_LD   264   // 256 + 8 fp16 pad -> row stride 528B (+4 banks/row)
#define HS_LD   136   // 128 + 8 fp16 pad -> row stride 272B (+4 banks/row)

__device__ __forceinline__ unsigned short f2h(float f){
    _Float16 h = (_Float16)f;                  // v_cvt_f16_f32, RNE
    union { _Float16 h; unsigned short u; } v; v.h = h; return v.u;
}
__device__ __forceinline__ unsigned pk2h(float a, float b){
    return (unsigned)f2h(a) | ((unsigned)f2h(b) << 16);
}

// Repack W1[256,128] / W2[128,64] (row-major fp32) into fp16 MFMA B-fragment
// order: lane's 8 B-elements contiguous (one 16B load).
//   W1p[((kt*8+nt)*64 + lane)*8 + j] = fp16(W1[kt*32 + (lane>>4)*8 + j][nt*16 + (lane&15)])
__global__ void repack_w(const float* __restrict__ W1,
                         const float* __restrict__ W2,
                         ushort_t* __restrict__ W1p,
                         ushort_t* __restrict__ W2p){
    int tid = blockIdx.x * 256 + threadIdx.x;
    if (tid < 8*8*64){
        int kt = tid >> 9, nt = (tid >> 6) & 7, l = tid & 63;
        int q = l >> 4, c = l & 15;
        ushort_t tmp[8];
        #pragma unroll
        for (int j = 0; j < 8; j++)
            tmp[j] = f2h(W1[(kt*32 + q*8 + j)*128 + nt*16 + c]);
        #pragma unroll
        for (int j = 0; j < 8; j++) W1p[tid*8 + j] = tmp[j];
    } else if (tid < 8*8*64 + 4*4*64){
        int t = tid - 8*8*64;
        int kt = t >> 8, nt = (t >> 6) & 3, l = t & 63;
        int q = l >> 4, c = l & 15;
        ushort_t tmp[8];
        #pragma unroll
        for (int j = 0; j < 8; j++)
            tmp[j] = f2h(W2[(kt*32 + q*8 + j)*64 + nt*16 + c]);
        #pragma unroll
        for (int j = 0; j < 8; j++) W2p[t*8 + j] = tmp[j];
    }
}

// 512 threads (8 waves), M_BLK=128, LDS 67.6 KB -> 2 blocks/CU = 16 waves/CU.
__global__ __launch_bounds__(512, 4)
void edge_mlp(const float* __restrict__ node_attr,
              const float* __restrict__ edge_attr,
              const float* __restrict__ global_attr,
              const float* __restrict__ node_mask,
              const float* __restrict__ edge_mask,
              const int*   __restrict__ edge_index,
              const int*   __restrict__ eg_index,
              const float* __restrict__ b1,
              const float* __restrict__ b2,
              const ushort_t* __restrict__ W1p,
              const ushort_t* __restrict__ W2p,
              float*       __restrict__ out){
    __shared__ ushort_t Xs[M_BLK * XS_LD];   // re-used as Hs after barrier
    ushort_t* Hs = Xs;                        // [M_BLK][HS_LD] overlay

    const int tid = threadIdx.x;
    const int e0  = blockIdx.x * M_BLK;

    // ---- seg0: edge_attr rows (fp32), coalesced float4, cvt->fp16 ----
    {
        const float4* src = (const float4*)(edge_attr + (size_t)e0 * 64);
        #pragma unroll
        for (int k = 0; k < 4; k++){
            int idx = tid + k*512;            // 0..2047 ; 16 float4 per row
            int r = idx >> 4, c = idx & 15;
            float4 v = src[idx];
            uint2 o; o.x = pk2h(v.x, v.y); o.y = pk2h(v.z, v.w);
            *(uint2*)&Xs[r*XS_LD + c*4] = o;
        }
    }
    // ---- seg3: global gather (16 distinct rows, L2-hot), direct eg_index ----
    {
        #pragma unroll
        for (int k = 0; k < 4; k++){
            int idx = tid + k*512; int r = idx >> 4, c = idx & 15;
            int g = eg_index[e0 + r];
            const float4* src = (const float4*)(global_attr + (size_t)g * 64);
            float4 v = src[c];
            uint2 o; o.x = pk2h(v.x, v.y); o.y = pk2h(v.z, v.w);
            *(uint2*)&Xs[r*XS_LD + 192 + c*4] = o;
        }
    }
    // ---- seg1/seg2: node gathers with node_mask scaling, direct edge_index ----
    {
        int r = tid >> 2, seg = (tid >> 1) & 1, half = tid & 1;
        int idx = edge_index[seg*E_TOTAL + e0 + r];
        float m = node_mask[idx];
        const float4* src = (const float4*)(node_attr + (size_t)idx * 64) + half*8;
        ushort_t* dst = &Xs[r*XS_LD + 64 + seg*64 + half*32];
        #pragma unroll
        for (int c2 = 0; c2 < 8; c2++){
            float4 v = src[c2];
            uint2 o; o.x = pk2h(v.x*m, v.y*m); o.y = pk2h(v.z*m, v.w*m);
            *(uint2*)(dst + c2*4) = o;
        }
    }
    __syncthreads();

    // ---- GEMM1: H[128,128] = X[128,256] @ W1 ; wave owns 4mt x 2nt ----
    const int w  = tid >> 6, lane = tid & 63;
    const int q  = lane >> 4, cc = lane & 15;
    const int mt0 = (w >> 2) * 4;   // 0 or 4
    const int nt0 = (w & 3) * 2;    // 0,2,4,6

    floatx4 acc[4][2];
    #pragma unroll
    for (int i = 0; i < 4; i++)
        #pragma unroll
        for (int j = 0; j < 2; j++) acc[i][j] = (floatx4){0.f,0.f,0.f,0.f};

    const short8* W1v = (const short8*)W1p;
    #pragma unroll
    for (int kt = 0; kt < 8; kt++){
        short8 b[2];
        #pragma unroll
        for (int j = 0; j < 2; j++) b[j] = W1v[(kt*8 + nt0 + j)*64 + lane];
        #pragma unroll
        for (int i = 0; i < 4; i++){
            const short8 a = *(const short8*)&Xs[((mt0 + i)*16 + cc)*XS_LD + kt*32 + q*8];
            #pragma unroll
            for (int j = 0; j < 2; j++)
                acc[i][j] = __builtin_amdgcn_mfma_f32_16x16x32_f16(a, b[j], acc[i][j], 0, 0, 0);
        }
    }
    __syncthreads();   // everyone done reading Xs before Hs overlay

    // ---- epilogue 1: +b1, relu, fp16 -> Hs (MFMA-A layout = row-major) ----
    #pragma unroll
    for (int j = 0; j < 2; j++){
        int col = (nt0 + j)*16 + cc;
        float bb = b1[col];
        #pragma unroll
        for (int i = 0; i < 4; i++){
            int rowb = (mt0 + i)*16 + q*4;
            #pragma unroll
            for (int r = 0; r < 4; r++){
                float v = acc[i][j][r] + bb;
                v = v > 0.f ? v : 0.f;
                Hs[(rowb + r)*HS_LD + col] = f2h(v);
            }
        }
    }
    __syncthreads();

    // ---- GEMM2: OUT[128,64] = H[128,128] @ W2 ; wave owns 2mt x 2nt ----
    const int mt20 = (w >> 1) * 2;  // 0,0,2,2,4,4,6,6
    const int nt20 = (w & 1) * 2;   // 0 or 2

    floatx4 acc2[2][2];
    #pragma unroll
    for (int i = 0; i < 2; i++)
        #pragma unroll
        for (int j = 0; j < 2; j++) acc2[i][j] = (floatx4){0.f,0.f,0.f,0.f};

    const short8* W2v = (const short8*)W2p;
    #pragma unroll
    for (int kt = 0; kt < 4; kt++){
        short8 b[2];
        #pragma unroll
        for (int j = 0; j < 2; j++) b[j] = W2v[(kt*4 + nt20 + j)*64 + lane];
        #pragma unroll
        for (int i = 0; i < 2; i++){
            const short8 a = *(const short8*)&Hs[((mt20 + i)*16 + cc)*HS_LD + kt*32 + q*8];
            #pragma unroll
            for (int j = 0; j < 2; j++)
                acc2[i][j] = __builtin_amdgcn_mfma_f32_16x16x32_f16(a, b[j], acc2[i][j], 0, 0, 0);
        }
    }

    // ---- epilogue 2: +b2, *edge_mask, store fp32 ----
    float bb2[2];
    #pragma unroll
    for (int j = 0; j < 2; j++) bb2[j] = b2[(nt20 + j)*16 + cc];
    #pragma unroll
    for (int i = 0; i < 2; i++){
        #pragma unroll
        for (int r = 0; r < 4; r++){
            int row = (mt20 + i)*16 + q*4 + r;
            float em = edge_mask[e0 + row];
            size_t base = (size_t)(e0 + row) * 64;
            #pragma unroll
            for (int j = 0; j < 2; j++){
                float v = (acc2[i][j][r] + bb2[j]) * em;
                out[base + (nt20 + j)*16 + cc] = v;
            }
        }
    }
}

extern "C" void kernel_launch(void* const* d_in, const int* in_sizes, int n_in,
                              void* d_out, int out_size, void* d_ws, size_t ws_size,
                              hipStream_t stream){
    const float* node_attr   = (const float*)d_in[0];
    const float* edge_attr   = (const float*)d_in[1];
    const float* global_attr = (const float*)d_in[2];
    const float* node_mask   = (const float*)d_in[3];
    const float* edge_mask   = (const float*)d_in[4];
    const int*   edge_index  = (const int*)d_in[5];
    const int*   eg_index    = (const int*)d_in[6];
    const float* W1          = (const float*)d_in[7];
    const float* b1          = (const float*)d_in[8];
    const float* W2          = (const float*)d_in[9];
    const float* b2          = (const float*)d_in[10];

    ushort_t* W1p = (ushort_t*)d_ws;            // 8*8*64*8 = 32768 elems (64 KB)
    ushort_t* W2p = W1p + 8*8*64*8;             // 4*4*64*8 =  8192 elems (16 KB)

    repack_w<<<20, 256, 0, stream>>>(W1, W2, W1p, W2p);
    edge_mlp<<<E_TOTAL / M_BLK, 512, 0, stream>>>(
        node_attr, edge_attr, global_attr, node_mask, edge_mask,
        edge_index, eg_index, b1, b2, W1p, W2p, (float*)d_out);
}